// Round 1
// baseline (1500.896 us; speedup 1.0000x reference)
//
#include <hip/hip_runtime.h>

#define VSZ 50257
#define DSZ 1024
#define TSZ 512
#define BSZ 4
#define HSZ 4096
#define VPAD 50304   // 393*128

typedef __attribute__((ext_vector_type(8))) __bf16 bf16x8;
typedef __attribute__((ext_vector_type(4))) float f32x4;

#define GLD16(gp, lp) __builtin_amdgcn_global_load_lds( \
  (const __attribute__((address_space(1))) unsigned int*)(gp), \
  (__attribute__((address_space(3))) unsigned int*)(lp), 16, 0, 0)

__device__ __forceinline__ float gelu_f(float x) {
  float x3 = x * x * x;
  float u = 0.7978845608028654f * (x + 0.044715f * x3);
  return 0.5f * x * (1.f + tanhf(u));
}

// -------- transpose + f32->bf16 convert: src (R x C) row-major -> dst (Cpad x R), zero-fill c>=C
__global__ void transpose_conv(const float* __restrict__ src, __bf16* __restrict__ dst,
                               int R, int C, int Cpad) {
  __shared__ float tile[32][33];
  int c0 = blockIdx.x * 32, r0 = blockIdx.y * 32;
  int tx = threadIdx.x, ty = threadIdx.y;
  for (int i = ty; i < 32; i += 8) {
    int c = c0 + tx;
    tile[i][tx] = (c < C) ? src[(size_t)(r0 + i) * C + c] : 0.f;
  }
  __syncthreads();
  for (int i = ty; i < 32; i += 8) {
    int dr = c0 + i;
    if (dr < Cpad) dst[(size_t)dr * R + r0 + tx] = (__bf16)tile[tx][i];
  }
}

// -------- encoder layer 1: t1[b][h] = gelu(dot(wte[tok_b], enc_w1[:,h]) + b1[h])
__global__ __launch_bounds__(256) void enc1_kernel(const int* __restrict__ ids,
                                                   const float* __restrict__ wte,
                                                   const float* __restrict__ w1,
                                                   const float* __restrict__ b1,
                                                   float* __restrict__ t1) {
  __shared__ float e0[DSZ];
  int b = blockIdx.x;
  int h = blockIdx.y * 256 + threadIdx.x;
  int tok = ids[b * TSZ + (TSZ - 1)];
  for (int i = threadIdx.x; i < DSZ; i += 256) e0[i] = wte[(size_t)tok * DSZ + i];
  __syncthreads();
  float s = b1[h];
  for (int d = 0; d < DSZ; ++d) s += e0[d] * w1[(size_t)d * HSZ + h];
  t1[b * HSZ + h] = gelu_f(s);
}

// -------- encoder layer 2: e[b][i] = dot(t1[b], enc_w2[:,i]) + b2[i]
__global__ __launch_bounds__(256) void enc2_kernel(const float* __restrict__ t1,
                                                   const float* __restrict__ w2,
                                                   const float* __restrict__ b2,
                                                   float* __restrict__ e) {
  __shared__ float tr[HSZ];
  int b = blockIdx.x;
  int i = blockIdx.y * 256 + threadIdx.x;
  for (int j = threadIdx.x; j < HSZ; j += 256) tr[j] = t1[b * HSZ + j];
  __syncthreads();
  float s = b2[i];
  for (int j = 0; j < HSZ; ++j) s += tr[j] * w2[(size_t)j * DSZ + i];
  e[b * DSZ + i] = s;
}

// -------- windows: win[b*T+t][j] = bf16(e[b][t+j])   (t+j < 1024 always)
__global__ void win_kernel(const float* __restrict__ e, __bf16* __restrict__ win) {
  int blk = blockIdx.x;               // b*512 + t
  int b = blk >> 9, t = blk & 511;
  const float* eb = e + b * DSZ;
  for (int j = threadIdx.x; j < 512; j += 256)
    win[(size_t)blk * 512 + j] = (__bf16)eb[t + j];
}

// -------- GEMM: C[m][n] = sum_k A[m][k]*B[n][k]  (both operands K-contiguous)
// MODE 0: out bf16 row-major [M][N], + bias[n], optional gelu
// MODE 1: lm head: m=v, n=b*T+t -> outF[1 + b*V*T + v*T + t], guard v<VSZ
template<int MODE, int GELU>
__global__ __launch_bounds__(256) void gemm128(
    const __bf16* __restrict__ A, const __bf16* __restrict__ Bm,
    const float* __restrict__ bias, __bf16* __restrict__ outB,
    float* __restrict__ outF, int M, int N, int K) {
  __shared__ __bf16 smA[128 * 32];
  __shared__ __bf16 smB[128 * 32];
  const int tid = threadIdx.x;
  const int lane = tid & 63;
  const int wave = tid >> 6;
  const int wr = (wave >> 1) * 64, wc = (wave & 1) * 64;
  const int m0 = blockIdx.y * 128, n0 = blockIdx.x * 128;
  const int l15 = lane & 15, l4 = lane >> 4;

  f32x4 acc[4][4];
#pragma unroll
  for (int i = 0; i < 4; ++i)
#pragma unroll
    for (int j = 0; j < 4; ++j) acc[i][j] = (f32x4){0.f, 0.f, 0.f, 0.f};

  const int srow = tid >> 2;          // 0..63
  const int scol = (tid & 3) * 8;     // k-elem offset
  const __bf16* Ag = A + (size_t)(m0 + srow) * K + scol;
  const __bf16* Bg = Bm + (size_t)(n0 + srow) * K + scol;

  for (int k0 = 0; k0 < K; k0 += 32) {
#pragma unroll
    for (int it = 0; it < 2; ++it) {
      GLD16(Ag + (size_t)it * 64 * K + k0, (char*)smA + it * 4096 + wave * 1024);
      GLD16(Bg + (size_t)it * 64 * K + k0, (char*)smB + it * 4096 + wave * 1024);
    }
    __syncthreads();   // compiler emits vmcnt(0) drain before barrier
    bf16x8 af[4], bfr[4];
#pragma unroll
    for (int mi = 0; mi < 4; ++mi)
      af[mi] = *(const bf16x8*)((const char*)smA + (wr + mi * 16 + l15) * 64 + l4 * 16);
#pragma unroll
    for (int ni = 0; ni < 4; ++ni)
      bfr[ni] = *(const bf16x8*)((const char*)smB + (wc + ni * 16 + l15) * 64 + l4 * 16);
#pragma unroll
    for (int mi = 0; mi < 4; ++mi)
#pragma unroll
      for (int ni = 0; ni < 4; ++ni)
        acc[mi][ni] = __builtin_amdgcn_mfma_f32_16x16x32_bf16(af[mi], bfr[ni], acc[mi][ni], 0, 0, 0);
    __syncthreads();
  }

  if (MODE == 0) {
#pragma unroll
    for (int ni = 0; ni < 4; ++ni) {
      int n = n0 + wc + ni * 16 + l15;
      float bv = bias[n];
#pragma unroll
      for (int mi = 0; mi < 4; ++mi) {
#pragma unroll
        for (int r = 0; r < 4; ++r) {
          int m = m0 + wr + mi * 16 + l4 * 4 + r;
          float v = acc[mi][ni][r] + bv;
          if (GELU) v = gelu_f(v);
          outB[(size_t)m * N + n] = (__bf16)v;
        }
      }
    }
  } else {
#pragma unroll
    for (int ni = 0; ni < 4; ++ni) {
      int n = n0 + wc + ni * 16 + l15;   // b*T + t
      int bb = n >> 9, tt = n & 511;
#pragma unroll
      for (int mi = 0; mi < 4; ++mi) {
        int vbase = m0 + wr + mi * 16 + l4 * 4;
#pragma unroll
        for (int r = 0; r < 4; ++r) {
          int v = vbase + r;
          if (v < VSZ)
            outF[1 + (size_t)bb * VSZ * TSZ + (size_t)v * TSZ + tt] = acc[mi][ni][r];
        }
      }
    }
  }
}

// -------- loss pass 1: per (v-chunk, pos) online logsumexp partials
#define VCHUNKS 32
#define CHUNK 1571   // 32*1571 = 50272 >= 50257
__global__ __launch_bounds__(256) void loss1_kernel(const float* __restrict__ out,
                                                    float* __restrict__ pm,
                                                    float* __restrict__ ps) {
  int chunk = blockIdx.x;
  int pos = blockIdx.y * 256 + threadIdx.x;   // b*512 + t
  int b = pos >> 9, t = pos & 511;
  const float* base = out + 1 + (size_t)b * VSZ * TSZ + t;
  int v0 = chunk * CHUNK;
  int v1 = v0 + CHUNK; if (v1 > VSZ) v1 = VSZ;
  float m = -1e30f, s = 0.f;
  for (int v = v0; v < v1; ++v) {
    float x = base[(size_t)v * TSZ];
    float nm = fmaxf(m, x);
    s = s * __expf(m - nm) + __expf(x - nm);
    m = nm;
  }
  pm[chunk * 2048 + pos] = m;
  ps[chunk * 2048 + pos] = s;
}

// -------- loss pass 2: merge partials, gather label logit, mean
__global__ __launch_bounds__(1024) void loss2_kernel(const float* __restrict__ out,
                                                     const int* __restrict__ labels,
                                                     const float* __restrict__ pm,
                                                     const float* __restrict__ ps,
                                                     float* __restrict__ dout) {
  __shared__ float red[1024];
  int tid = threadIdx.x;
  float acc = 0.f;
  for (int pos = tid; pos < 2048; pos += 1024) {
    float m = -1e30f, s = 0.f;
    for (int c = 0; c < VCHUNKS; ++c) {
      float cm = pm[c * 2048 + pos], cs = ps[c * 2048 + pos];
      float nm = fmaxf(m, cm);
      s = s * __expf(m - nm) + cs * __expf(cm - nm);
      m = nm;
    }
    float lse = m + logf(s);
    int b = pos >> 9, t = pos & 511;
    int lab = labels[pos];
    float x = out[1 + (size_t)b * VSZ * TSZ + (size_t)lab * TSZ + t];
    acc += (lse - x);
  }
  red[tid] = acc;
  __syncthreads();
  for (int off = 512; off; off >>= 1) {
    if (tid < off) red[tid] += red[tid + off];
    __syncthreads();
  }
  if (tid == 0) dout[0] = red[0] / 2048.f;
}

extern "C" void kernel_launch(void* const* d_in, const int* in_sizes, int n_in,
                              void* d_out, int out_size, void* d_ws, size_t ws_size,
                              hipStream_t stream) {
  const int* input_ids = (const int*)d_in[0];
  const int* labels    = (const int*)d_in[1];
  const float* wte     = (const float*)d_in[2];
  const float* enc_w1  = (const float*)d_in[3];
  const float* enc_b1  = (const float*)d_in[4];
  const float* enc_w2  = (const float*)d_in[5];
  const float* enc_b2  = (const float*)d_in[6];
  const float* proj_w  = (const float*)d_in[7];
  const float* proj_b  = (const float*)d_in[8];
  const float* dec_w1  = (const float*)d_in[9];
  const float* dec_b1  = (const float*)d_in[10];
  const float* dec_w2  = (const float*)d_in[11];
  const float* dec_b2  = (const float*)d_in[12];
  const float* lm_w    = (const float*)d_in[13];
  float* outF = (float*)d_out;

  char* w = (char*)d_ws;
  size_t off = 0;
  __bf16* lmT   = (__bf16*)(w + off); off += (size_t)VPAD * DSZ * 2;      // 103.0 MB
  __bf16* w1T   = (__bf16*)(w + off); off += (size_t)HSZ * DSZ * 2;       // 8 MB
  __bf16* w2T   = (__bf16*)(w + off); off += (size_t)DSZ * HSZ * 2;       // 8 MB
  __bf16* projT = (__bf16*)(w + off); off += (size_t)DSZ * 512 * 2;       // 1 MB
  __bf16* win   = (__bf16*)(w + off); off += (size_t)2048 * 512 * 2;      // 2 MB
  __bf16* pbuf  = (__bf16*)(w + off); off += (size_t)2048 * DSZ * 2;      // 4 MB
  __bf16* abuf  = (__bf16*)(w + off); off += (size_t)2048 * HSZ * 2;      // 16 MB
  __bf16* dbuf  = (__bf16*)(w + off); off += (size_t)2048 * DSZ * 2;      // 4 MB
  float* t1     = (float*)(w + off);  off += (size_t)BSZ * HSZ * 4;
  float* e      = (float*)(w + off);  off += (size_t)BSZ * DSZ * 4;
  float* pm     = (float*)(w + off);  off += (size_t)VCHUNKS * 2048 * 4;
  float* ps     = (float*)(w + off);  off += (size_t)VCHUNKS * 2048 * 4;
  (void)ws_size; (void)in_sizes; (void)n_in; (void)out_size;

  dim3 tb(32, 8);
  // weight transposes (f32 -> bf16, K-contiguous)
  transpose_conv<<<dim3(VPAD / 32, DSZ / 32), tb, 0, stream>>>(lm_w, lmT, DSZ, VSZ, VPAD);
  transpose_conv<<<dim3(HSZ / 32, DSZ / 32), tb, 0, stream>>>(dec_w1, w1T, DSZ, HSZ, HSZ);
  transpose_conv<<<dim3(DSZ / 32, HSZ / 32), tb, 0, stream>>>(dec_w2, w2T, HSZ, DSZ, DSZ);
  transpose_conv<<<dim3(DSZ / 32, 512 / 32), tb, 0, stream>>>(proj_w, projT, 512, DSZ, DSZ);

  // encoder on last token only
  enc1_kernel<<<dim3(BSZ, HSZ / 256), 256, 0, stream>>>(input_ids, wte, enc_w1, enc_b1, t1);
  enc2_kernel<<<dim3(BSZ, DSZ / 256), 256, 0, stream>>>(t1, enc_w2, enc_b2, e);
  win_kernel<<<2048, 256, 0, stream>>>(e, win);

  // GEMM chain (M rows x N cols, both operands [rows][K])
  gemm128<0, 0><<<dim3(DSZ / 128, 2048 / 128), 256, 0, stream>>>(win, projT, proj_b, pbuf, nullptr, 2048, DSZ, 512);
  gemm128<0, 1><<<dim3(HSZ / 128, 2048 / 128), 256, 0, stream>>>(pbuf, w1T, dec_b1, abuf, nullptr, 2048, HSZ, DSZ);
  gemm128<0, 0><<<dim3(DSZ / 128, 2048 / 128), 256, 0, stream>>>(abuf, w2T, dec_b2, dbuf, nullptr, 2048, DSZ, HSZ);
  gemm128<1, 0><<<dim3(2048 / 128, VPAD / 128), 256, 0, stream>>>(lmT, dbuf, nullptr, nullptr, outF, VPAD, 2048, DSZ);

  // loss
  loss1_kernel<<<dim3(VCHUNKS, 2048 / 256), 256, 0, stream>>>(outF, pm, ps);
  loss2_kernel<<<1, 1024, 0, stream>>>(outF, labels, pm, ps, outF);
}

// Round 2
// 814.243 us; speedup vs baseline: 1.8433x; 1.8433x over previous
//
#include <hip/hip_runtime.h>

#define VSZ 50257
#define DSZ 1024
#define TSZ 512
#define BSZ 4
#define HSZ 4096
#define VPAD 50304   // 393*128
#define NCH (VPAD / 64)   // 786 v-stripes of 64
#define NPOS 2048

typedef __attribute__((ext_vector_type(8))) __bf16 bf16x8;
typedef __attribute__((ext_vector_type(4))) float f32x4;

#define GLD16(gp, lp) __builtin_amdgcn_global_load_lds( \
  (const __attribute__((address_space(1))) unsigned int*)(gp), \
  (__attribute__((address_space(3))) unsigned int*)(lp), 16, 0, 0)

__device__ __forceinline__ float gelu_f(float x) {
  float x3 = x * x * x;
  float u = 0.7978845608028654f * (x + 0.044715f * x3);
  return 0.5f * x * (1.f + tanhf(u));
}

// -------- transpose + f32->bf16 convert: src (R x C) row-major -> dst (Cpad x R), zero-fill c>=C
__global__ void transpose_conv(const float* __restrict__ src, __bf16* __restrict__ dst,
                               int R, int C, int Cpad) {
  __shared__ float tile[32][33];
  int c0 = blockIdx.x * 32, r0 = blockIdx.y * 32;
  int tx = threadIdx.x, ty = threadIdx.y;
  for (int i = ty; i < 32; i += 8) {
    int c = c0 + tx;
    tile[i][tx] = (c < C) ? src[(size_t)(r0 + i) * C + c] : 0.f;
  }
  __syncthreads();
  for (int i = ty; i < 32; i += 8) {
    int dr = c0 + i;
    if (dr < Cpad) dst[(size_t)dr * R + r0 + tx] = (__bf16)tile[tx][i];
  }
}

// -------- encoder layer 1 partials: K-split dot over d-chunk of 128
#define KS1 8
__global__ __launch_bounds__(256) void enc1p_kernel(const int* __restrict__ ids,
                                                    const float* __restrict__ wte,
                                                    const float* __restrict__ w1,
                                                    float* __restrict__ t1p) {
  int b = blockIdx.x;
  int h = blockIdx.y * 256 + threadIdx.x;
  int kc = blockIdx.z;
  int tok = ids[b * TSZ + (TSZ - 1)];
  const float* ev = wte + (size_t)tok * DSZ + kc * (DSZ / KS1);
  const float* w = w1 + (size_t)kc * (DSZ / KS1) * HSZ + h;
  float s = 0.f;
#pragma unroll 4
  for (int d = 0; d < DSZ / KS1; ++d) s += ev[d] * w[(size_t)d * HSZ];
  t1p[((size_t)(b * KS1 + kc)) * HSZ + h] = s;
}

__global__ __launch_bounds__(256) void enc1c_kernel(const float* __restrict__ t1p,
                                                    const float* __restrict__ b1,
                                                    float* __restrict__ t1) {
  int idx = blockIdx.x * 256 + threadIdx.x;   // b*HSZ + h
  int b = idx >> 12, h = idx & (HSZ - 1);
  float s = b1[h];
#pragma unroll
  for (int kc = 0; kc < KS1; ++kc) s += t1p[((size_t)(b * KS1 + kc)) * HSZ + h];
  t1[idx] = gelu_f(s);
}

// -------- encoder layer 2 partials: K-split over j-chunk of 256
#define KS2 16
__global__ __launch_bounds__(256) void enc2p_kernel(const float* __restrict__ t1,
                                                    const float* __restrict__ w2,
                                                    float* __restrict__ ep) {
  int b = blockIdx.x;
  int i = blockIdx.y * 256 + threadIdx.x;
  int kc = blockIdx.z;
  const float* tb = t1 + (size_t)b * HSZ + kc * (HSZ / KS2);
  const float* w = w2 + (size_t)kc * (HSZ / KS2) * DSZ + i;
  float s = 0.f;
#pragma unroll 4
  for (int j = 0; j < HSZ / KS2; ++j) s += tb[j] * w[(size_t)j * DSZ];
  ep[((size_t)(b * KS2 + kc)) * DSZ + i] = s;
}

__global__ __launch_bounds__(256) void enc2c_kernel(const float* __restrict__ ep,
                                                    const float* __restrict__ b2,
                                                    float* __restrict__ e) {
  int idx = blockIdx.x * 256 + threadIdx.x;   // b*DSZ + i
  int b = idx >> 10, i = idx & (DSZ - 1);
  float s = b2[i];
#pragma unroll
  for (int kc = 0; kc < KS2; ++kc) s += ep[((size_t)(b * KS2 + kc)) * DSZ + i];
  e[idx] = s;
}

// -------- windows: win[b*T+t][j] = bf16(e[b][t+j])   (t+j < 1024 always)
__global__ void win_kernel(const float* __restrict__ e, __bf16* __restrict__ win) {
  int blk = blockIdx.x;               // b*512 + t
  int b = blk >> 9, t = blk & 511;
  const float* eb = e + b * DSZ;
  for (int j = threadIdx.x; j < 512; j += 256)
    win[(size_t)blk * 512 + j] = (__bf16)eb[t + j];
}

// -------- GEMM: C[m][n] = sum_k A[m][k]*B[n][k]  (both operands K-contiguous)
// MODE 0: out bf16 row-major [M][N], + bias[n], optional gelu
// MODE 1: lm head: m=v, n=b*T+t -> outF[1 + b*V*T + v*T + t], guard v<VSZ,
//         plus fused softmax partials: per 64-v stripe & column, (max, sumexp)
template<int MODE, int GELU>
__global__ __launch_bounds__(256) void gemm128(
    const __bf16* __restrict__ A, const __bf16* __restrict__ Bm,
    const float* __restrict__ bias, __bf16* __restrict__ outB,
    float* __restrict__ outF, float* __restrict__ pm, float* __restrict__ ps,
    int M, int N, int K) {
  __shared__ __bf16 smA[128 * 32];
  __shared__ __bf16 smB[128 * 32];
  const int tid = threadIdx.x;
  const int lane = tid & 63;
  const int wave = tid >> 6;
  const int wr = (wave >> 1) * 64, wc = (wave & 1) * 64;
  const int m0 = blockIdx.y * 128, n0 = blockIdx.x * 128;
  const int l15 = lane & 15, l4 = lane >> 4;

  f32x4 acc[4][4];
#pragma unroll
  for (int i = 0; i < 4; ++i)
#pragma unroll
    for (int j = 0; j < 4; ++j) acc[i][j] = (f32x4){0.f, 0.f, 0.f, 0.f};

  const int srow = tid >> 2;          // 0..63
  const int scol = (tid & 3) * 8;     // k-elem offset
  const __bf16* Ag = A + (size_t)(m0 + srow) * K + scol;
  const __bf16* Bg = Bm + (size_t)(n0 + srow) * K + scol;

  for (int k0 = 0; k0 < K; k0 += 32) {
#pragma unroll
    for (int it = 0; it < 2; ++it) {
      GLD16(Ag + (size_t)it * 64 * K + k0, (char*)smA + it * 4096 + wave * 1024);
      GLD16(Bg + (size_t)it * 64 * K + k0, (char*)smB + it * 4096 + wave * 1024);
    }
    __syncthreads();
    bf16x8 af[4], bfr[4];
#pragma unroll
    for (int mi = 0; mi < 4; ++mi)
      af[mi] = *(const bf16x8*)((const char*)smA + (wr + mi * 16 + l15) * 64 + l4 * 16);
#pragma unroll
    for (int ni = 0; ni < 4; ++ni)
      bfr[ni] = *(const bf16x8*)((const char*)smB + (wc + ni * 16 + l15) * 64 + l4 * 16);
#pragma unroll
    for (int mi = 0; mi < 4; ++mi)
#pragma unroll
      for (int ni = 0; ni < 4; ++ni)
        acc[mi][ni] = __builtin_amdgcn_mfma_f32_16x16x32_bf16(af[mi], bfr[ni], acc[mi][ni], 0, 0, 0);
    __syncthreads();
  }

  if (MODE == 0) {
#pragma unroll
    for (int ni = 0; ni < 4; ++ni) {
      int n = n0 + wc + ni * 16 + l15;
      float bv = bias[n];
#pragma unroll
      for (int mi = 0; mi < 4; ++mi) {
#pragma unroll
        for (int r = 0; r < 4; ++r) {
          int m = m0 + wr + mi * 16 + l4 * 4 + r;
          float v = acc[mi][ni][r] + bv;
          if (GELU) v = gelu_f(v);
          outB[(size_t)m * N + n] = (__bf16)v;
        }
      }
    }
  } else {
    const int ch = (m0 + wr) >> 6;   // global 64-v stripe index
#pragma unroll
    for (int ni = 0; ni < 4; ++ni) {
      int n = n0 + wc + ni * 16 + l15;   // pos = b*T + t
      int bb = n >> 9, tt = n & 511;
      float mloc = -1e30f, sloc = 0.f;
#pragma unroll
      for (int mi = 0; mi < 4; ++mi) {
        int vbase = m0 + wr + mi * 16 + l4 * 4;
#pragma unroll
        for (int r = 0; r < 4; ++r) {
          int v = vbase + r;
          if (v < VSZ) {
            float x = acc[mi][ni][r];
            outF[1 + (size_t)bb * VSZ * TSZ + (size_t)v * TSZ + tt] = x;
            mloc = fmaxf(mloc, x);
          }
        }
      }
#pragma unroll
      for (int mi = 0; mi < 4; ++mi) {
        int vbase = m0 + wr + mi * 16 + l4 * 4;
#pragma unroll
        for (int r = 0; r < 4; ++r) {
          if (vbase + r < VSZ) sloc += __expf(acc[mi][ni][r] - mloc);
        }
      }
      // online merge across the 4 lanes (l4 = lane bits 4,5) sharing this column
#pragma unroll
      for (int off = 16; off <= 32; off <<= 1) {
        float mo = __shfl_xor(mloc, off, 64);
        float so = __shfl_xor(sloc, off, 64);
        float nm = fmaxf(mloc, mo);
        sloc = sloc * __expf(mloc - nm) + so * __expf(mo - nm);
        mloc = nm;
      }
      if (l4 == 0) {
        pm[(size_t)ch * NPOS + n] = mloc;
        ps[(size_t)ch * NPOS + n] = sloc;
      }
    }
  }
}

// -------- merge softmax partials per position, gather label logit
__global__ __launch_bounds__(256) void lsemerge_kernel(const float* __restrict__ pm,
                                                       const float* __restrict__ ps,
                                                       const float* __restrict__ outF,
                                                       const int* __restrict__ labels,
                                                       float* __restrict__ contrib) {
  int pos = blockIdx.x * 256 + threadIdx.x;   // 0..2047
  float m = -1e30f, s = 0.f;
  for (int c = 0; c < NCH; ++c) {
    float cm = pm[(size_t)c * NPOS + pos];
    float cs = ps[(size_t)c * NPOS + pos];
    float nm = fmaxf(m, cm);
    s = s * __expf(m - nm) + cs * __expf(cm - nm);
    m = nm;
  }
  float lse = m + logf(s);
  int b = pos >> 9, t = pos & 511;
  int lab = labels[pos];
  float x = outF[1 + (size_t)b * VSZ * TSZ + (size_t)lab * TSZ + t];
  contrib[pos] = lse - x;
}

__global__ __launch_bounds__(256) void lossfinal_kernel(const float* __restrict__ contrib,
                                                        float* __restrict__ dout) {
  __shared__ float red[256];
  int tid = threadIdx.x;
  float a = 0.f;
  for (int i = tid; i < NPOS; i += 256) a += contrib[i];
  red[tid] = a;
  __syncthreads();
  for (int off = 128; off; off >>= 1) {
    if (tid < off) red[tid] += red[tid + off];
    __syncthreads();
  }
  if (tid == 0) dout[0] = red[0] / (float)NPOS;
}

extern "C" void kernel_launch(void* const* d_in, const int* in_sizes, int n_in,
                              void* d_out, int out_size, void* d_ws, size_t ws_size,
                              hipStream_t stream) {
  const int* input_ids = (const int*)d_in[0];
  const int* labels    = (const int*)d_in[1];
  const float* wte     = (const float*)d_in[2];
  const float* enc_w1  = (const float*)d_in[3];
  const float* enc_b1  = (const float*)d_in[4];
  const float* enc_w2  = (const float*)d_in[5];
  const float* enc_b2  = (const float*)d_in[6];
  const float* proj_w  = (const float*)d_in[7];
  const float* proj_b  = (const float*)d_in[8];
  const float* dec_w1  = (const float*)d_in[9];
  const float* dec_b1  = (const float*)d_in[10];
  const float* dec_w2  = (const float*)d_in[11];
  const float* dec_b2  = (const float*)d_in[12];
  const float* lm_w    = (const float*)d_in[13];
  float* outF = (float*)d_out;

  char* w = (char*)d_ws;
  size_t off = 0;
  __bf16* lmT   = (__bf16*)(w + off); off += (size_t)VPAD * DSZ * 2;      // 103.0 MB
  __bf16* w1T   = (__bf16*)(w + off); off += (size_t)HSZ * DSZ * 2;       // 8 MB
  __bf16* w2T   = (__bf16*)(w + off); off += (size_t)DSZ * HSZ * 2;       // 8 MB
  __bf16* projT = (__bf16*)(w + off); off += (size_t)DSZ * 512 * 2;       // 1 MB
  __bf16* win   = (__bf16*)(w + off); off += (size_t)2048 * 512 * 2;      // 2 MB
  __bf16* pbuf  = (__bf16*)(w + off); off += (size_t)2048 * DSZ * 2;      // 4 MB
  __bf16* abuf  = (__bf16*)(w + off); off += (size_t)2048 * HSZ * 2;      // 16 MB
  __bf16* dbuf  = (__bf16*)(w + off); off += (size_t)2048 * DSZ * 2;      // 4 MB
  float* t1     = (float*)(w + off);  off += (size_t)BSZ * HSZ * 4;
  float* e      = (float*)(w + off);  off += (size_t)BSZ * DSZ * 4;
  float* t1p    = (float*)(w + off);  off += (size_t)BSZ * KS1 * HSZ * 4;   // 512 KB
  float* ep     = (float*)(w + off);  off += (size_t)BSZ * KS2 * DSZ * 4;   // 256 KB
  float* contrib= (float*)(w + off);  off += (size_t)NPOS * 4;
  // softmax partials alias abuf (free after gemm3): 786*2048*4*2 = 12.9 MB <= 16 MB
  float* pm = (float*)abuf;
  float* ps = pm + (size_t)NCH * NPOS;
  (void)ws_size; (void)in_sizes; (void)n_in; (void)out_size;

  dim3 tb(32, 8);
  // weight transposes (f32 -> bf16, K-contiguous)
  transpose_conv<<<dim3(VPAD / 32, DSZ / 32), tb, 0, stream>>>(lm_w, lmT, DSZ, VSZ, VPAD);
  transpose_conv<<<dim3(HSZ / 32, DSZ / 32), tb, 0, stream>>>(dec_w1, w1T, DSZ, HSZ, HSZ);
  transpose_conv<<<dim3(DSZ / 32, HSZ / 32), tb, 0, stream>>>(dec_w2, w2T, HSZ, DSZ, DSZ);
  transpose_conv<<<dim3(DSZ / 32, 512 / 32), tb, 0, stream>>>(proj_w, projT, 512, DSZ, DSZ);

  // encoder on last token only (K-split for parallelism)
  enc1p_kernel<<<dim3(BSZ, HSZ / 256, KS1), 256, 0, stream>>>(input_ids, wte, enc_w1, t1p);
  enc1c_kernel<<<dim3(BSZ * HSZ / 256), 256, 0, stream>>>(t1p, enc_b1, t1);
  enc2p_kernel<<<dim3(BSZ, DSZ / 256, KS2), 256, 0, stream>>>(t1, enc_w2, ep);
  enc2c_kernel<<<dim3(BSZ * DSZ / 256), 256, 0, stream>>>(ep, enc_b2, e);
  win_kernel<<<2048, 256, 0, stream>>>(e, win);

  // GEMM chain (M rows x N cols, both operands [rows][K])
  gemm128<0, 0><<<dim3(DSZ / 128, 2048 / 128), 256, 0, stream>>>(win, projT, proj_b, pbuf, nullptr, nullptr, nullptr, 2048, DSZ, 512);
  gemm128<0, 1><<<dim3(HSZ / 128, 2048 / 128), 256, 0, stream>>>(pbuf, w1T, dec_b1, abuf, nullptr, nullptr, nullptr, 2048, HSZ, DSZ);
  gemm128<0, 0><<<dim3(DSZ / 128, 2048 / 128), 256, 0, stream>>>(abuf, w2T, dec_b2, dbuf, nullptr, nullptr, nullptr, 2048, DSZ, HSZ);
  // lm head with fused softmax partials (pm/ps alias abuf, free by now)
  gemm128<1, 0><<<dim3(2048 / 128, VPAD / 128), 256, 0, stream>>>(lmT, dbuf, nullptr, nullptr, outF, pm, ps, VPAD, 2048, DSZ);

  // loss: merge partials + mean
  lsemerge_kernel<<<dim3(NPOS / 256), 256, 0, stream>>>(pm, ps, outF, labels, contrib);
  lossfinal_kernel<<<1, 256, 0, stream>>>(contrib, outF);
}